// Round 13
// baseline (90.666 us; speedup 1.0000x reference)
//
#include <hip/hip_runtime.h>
#include <hip/hip_bf16.h>
#include <math.h>

#define N_NODES 50000
#define K_COMP  32
#define G_DIM   512
#define E_EDGES 400000
#define OUT_DIM 8
#define EPSV    1e-8f

#define NPB 32                                  // nodes per node-kernel block
#define NB_NODE ((N_NODES + NPB - 1) / NPB)     // 1563
#define NB_E1   ((E_EDGES + 255) / 256)         // 1563 (1 edge/thread)
#define NB_CE   ((E_EDGES / 2 + 255) / 256)     // 782  (2 edges/thread)

typedef __attribute__((ext_vector_type(8))) short short8;
typedef __attribute__((ext_vector_type(8))) unsigned short ushort8;
typedef __attribute__((ext_vector_type(4))) unsigned short ushort4v;
typedef __attribute__((ext_vector_type(4))) float f32x4;

// ---------------- ws layout (float-indexed offsets) ----------------
// srcRec[n]: 32 floats = [0:8) xl f32 | [8:24) P bf16x32 | pad   (128B aligned)
// dstRec[n]: 32 floats = [0:8) xr f32 | [8:24) logP bf16x32 | pad
static const size_t OFF_T    = 0;                               // bf16 table 80*512 ushort (fragment-major)
static const size_t OFF_Q3   = OFF_T + 80 * 512;
static const size_t OFF_SRC  = OFF_Q3 + 64;                     // N*32 floats, 128B-aligned
static const size_t OFF_DST  = OFF_SRC + (size_t)N_NODES * 32;
static const size_t OFF_CON  = OFF_DST + (size_t)N_NODES * 32;  // E floats
static const size_t OFF_DEN  = OFF_CON + E_EDGES;               // N floats
static const size_t OFF_PLL  = OFF_DEN + N_NODES;               // NB_NODE*4 wave partials
static const size_t OFF_PCE  = OFF_PLL + 8192;                  // NB_CE partials
static const size_t OFF_TK   = OFF_PCE + 1024;                  // ticket (uint)

__device__ __forceinline__ unsigned short f2bf(float f) {
    __hip_bfloat16 h = __float2bfloat16(f);
    return *(unsigned short*)&h;
}
__device__ __forceinline__ float bf2f(unsigned short u) {
    unsigned v = ((unsigned)u) << 16;
    return __uint_as_float(v);
}

// ---------------- prep: fragment-major bf16 table + q3 + zero den/ticket -----
__global__ __launch_bounds__(256)
void prep_kernel(const float* __restrict__ Var, const float* __restrict__ Mu,
                 const float* __restrict__ Wl, const float* __restrict__ Wr,
                 unsigned short* __restrict__ Tb, float* __restrict__ den,
                 float* __restrict__ q3, unsigned* __restrict__ ticket) {
    int idx = blockIdx.x * 256 + threadIdx.x;
    if (idx < 80 * 512) {
        int r = idx >> 9;        // logical out-row 0..79
        int g = idx & 511;       // logical k 0..511
        float v;
        if (r < 32)      v = 1.0f / Var[r * 512 + g];
        else if (r < 64) { int k = r - 32; v = Mu[k * 512 + g] / Var[k * 512 + g]; }
        else if (r < 72) { int o = r - 64; v = Wl[g * 8 + o]; }
        else             { int o = r - 72; v = Wr[g * 8 + o]; }
        int dest = ((g >> 5) * 5 + (r >> 4)) * 512 + (r & 15) * 32 + (((g & 31) >> 3) << 3) + (g & 7);
        Tb[dest] = f2bf(v);
    }
    if (idx < N_NODES) den[idx] = 0.0f;
    if (idx == 0) *ticket = 0u;

    if (blockIdx.x < 32) {
        int k = blockIdx.x;
        int t = threadIdx.x;
        float s = 0.0f;
        for (int g = t; g < 512; g += 256) {
            float mu = Mu[k * 512 + g];
            s += mu * mu / Var[k * 512 + g];
        }
        for (int off = 32; off; off >>= 1) s += __shfl_down(s, off);
        __shared__ float sQ[4];
        if ((t & 63) == 0) sQ[t >> 6] = s;
        __syncthreads();
        if (t == 0) q3[k] = sQ[0] + sQ[1] + sQ[2] + sQ[3];
    }
}

// ---------------- fused node kernel (MFMA, k-split x4, 2 node-tiles/wave) ----
__global__ __launch_bounds__(256, 4)
void node_kernel(const float* __restrict__ X, const float* __restrict__ W,
                 const float* __restrict__ S, const float* __restrict__ bl,
                 const float* __restrict__ br, const unsigned short* __restrict__ Tb,
                 const float* __restrict__ q3, float* __restrict__ outP,
                 float* __restrict__ srcRec, float* __restrict__ dstRec,
                 float* __restrict__ pll) {
    __shared__ float sAccH[4][NPB][80];   // 40960 B exactly

    const int t = threadIdx.x;
    const int lane = t & 63;
    const int wq = t >> 6;        // K-quarter 0..3
    const int col = lane & 15;
    const int kg  = lane >> 4;    // 0..3

    const int n0 = blockIdx.x * NPB;
    int nodeA = n0 + col;
    int nodeB = n0 + 16 + col;
    if (nodeA >= N_NODES) nodeA = N_NODES - 1;   // tail clamp (loads only)
    if (nodeB >= N_NODES) nodeB = N_NODES - 1;
    const float* xrowA = X + (size_t)nodeA * 512 + wq * 128 + kg * 8;
    const float* xrowB = X + (size_t)nodeB * 512 + wq * 128 + kg * 8;

    f32x4 accA[5], accB[5];
#pragma unroll
    for (int i = 0; i < 5; ++i) {
        accA[i] = (f32x4){0.f, 0.f, 0.f, 0.f};
        accB[i] = (f32x4){0.f, 0.f, 0.f, 0.f};
    }

#pragma unroll
    for (int it = 0; it < 4; ++it) {
        const unsigned short* bbase =
            Tb + (size_t)(wq * 4 + it) * 5 * 512 + col * 32 + kg * 8;
        short8 b0 = *(const short8*)(bbase);
        short8 b1 = *(const short8*)(bbase + 512);
        short8 b2 = *(const short8*)(bbase + 1024);
        short8 b3 = *(const short8*)(bbase + 1536);
        short8 b4 = *(const short8*)(bbase + 2048);

        float4 va0 = *(const float4*)(xrowA + it * 32);
        float4 va1 = *(const float4*)(xrowA + it * 32 + 4);
        float4 vb0 = *(const float4*)(xrowB + it * 32);
        float4 vb1 = *(const float4*)(xrowB + it * 32 + 4);

        short8 axA, axA2, axB, axB2;
        axA[0] = (short)f2bf(va0.x); axA[1] = (short)f2bf(va0.y);
        axA[2] = (short)f2bf(va0.z); axA[3] = (short)f2bf(va0.w);
        axA[4] = (short)f2bf(va1.x); axA[5] = (short)f2bf(va1.y);
        axA[6] = (short)f2bf(va1.z); axA[7] = (short)f2bf(va1.w);
        axA2[0] = (short)f2bf(va0.x * va0.x); axA2[1] = (short)f2bf(va0.y * va0.y);
        axA2[2] = (short)f2bf(va0.z * va0.z); axA2[3] = (short)f2bf(va0.w * va0.w);
        axA2[4] = (short)f2bf(va1.x * va1.x); axA2[5] = (short)f2bf(va1.y * va1.y);
        axA2[6] = (short)f2bf(va1.z * va1.z); axA2[7] = (short)f2bf(va1.w * va1.w);
        axB[0] = (short)f2bf(vb0.x); axB[1] = (short)f2bf(vb0.y);
        axB[2] = (short)f2bf(vb0.z); axB[3] = (short)f2bf(vb0.w);
        axB[4] = (short)f2bf(vb1.x); axB[5] = (short)f2bf(vb1.y);
        axB[6] = (short)f2bf(vb1.z); axB[7] = (short)f2bf(vb1.w);
        axB2[0] = (short)f2bf(vb0.x * vb0.x); axB2[1] = (short)f2bf(vb0.y * vb0.y);
        axB2[2] = (short)f2bf(vb0.z * vb0.z); axB2[3] = (short)f2bf(vb0.w * vb0.w);
        axB2[4] = (short)f2bf(vb1.x * vb1.x); axB2[5] = (short)f2bf(vb1.y * vb1.y);
        axB2[6] = (short)f2bf(vb1.z * vb1.z); axB2[7] = (short)f2bf(vb1.w * vb1.w);

        accA[0] = __builtin_amdgcn_mfma_f32_16x16x32_bf16(axA2, b0, accA[0], 0, 0, 0);
        accB[0] = __builtin_amdgcn_mfma_f32_16x16x32_bf16(axB2, b0, accB[0], 0, 0, 0);
        accA[1] = __builtin_amdgcn_mfma_f32_16x16x32_bf16(axA2, b1, accA[1], 0, 0, 0);
        accB[1] = __builtin_amdgcn_mfma_f32_16x16x32_bf16(axB2, b1, accB[1], 0, 0, 0);
        accA[2] = __builtin_amdgcn_mfma_f32_16x16x32_bf16(axA,  b2, accA[2], 0, 0, 0);
        accB[2] = __builtin_amdgcn_mfma_f32_16x16x32_bf16(axB,  b2, accB[2], 0, 0, 0);
        accA[3] = __builtin_amdgcn_mfma_f32_16x16x32_bf16(axA,  b3, accA[3], 0, 0, 0);
        accB[3] = __builtin_amdgcn_mfma_f32_16x16x32_bf16(axB,  b3, accB[3], 0, 0, 0);
        accA[4] = __builtin_amdgcn_mfma_f32_16x16x32_bf16(axA,  b4, accA[4], 0, 0, 0);
        accB[4] = __builtin_amdgcn_mfma_f32_16x16x32_bf16(axB,  b4, accB[4], 0, 0, 0);
    }

    // ---- scatter partial accumulators (per K-quarter, both tiles) ----
#pragma unroll
    for (int ot = 0; ot < 5; ++ot)
#pragma unroll
        for (int r = 0; r < 4; ++r) {
            sAccH[wq][kg * 4 + r][ot * 16 + col]      = accA[ot][r];
            sAccH[wq][16 + kg * 4 + r][ot * 16 + col] = accB[ot][r];
        }
    __syncthreads();

    // ---- epilogue: 8 threads per node; thread handles k = j*4 .. j*4+3 ----
    const int nn = t >> 3;        // 0..31
    const int j = t & 7;          // 0..7
    const int n = n0 + nn;
    const bool valid = n < N_NODES;
    const int nc = valid ? n : N_NODES - 1;

    float sv = S[nc];
    float sv2 = sv * sv;
    float4 wv4 = *(const float4*)(W + (size_t)nc * 32 + j * 4);
    float w[4] = {wv4.x, wv4.y, wv4.z, wv4.w};
    float wm = fmaxf(fmaxf(w[0], w[1]), fmaxf(w[2], w[3]));
    wm = fmaxf(wm, __shfl_xor(wm, 1));
    wm = fmaxf(wm, __shfl_xor(wm, 2));
    wm = fmaxf(wm, __shfl_xor(wm, 4));
    float p[4], ps = 0.0f;
#pragma unroll
    for (int i = 0; i < 4; ++i) { p[i] = __expf(w[i] - wm); ps += p[i]; }
    ps += __shfl_xor(ps, 1);
    ps += __shfl_xor(ps, 2);
    ps += __shfl_xor(ps, 4);
    float inv = 1.0f / ps;

    float pv[4];
    ushort4v pb, lb;
    float ll = 0.0f;
#pragma unroll
    for (int i = 0; i < 4; ++i) {
        int k = j * 4 + i;
        float P_ = p[i] * inv;
        pv[i] = P_;
        pb[i] = f2bf(P_);
        lb[i] = f2bf(__logf(P_ + EPSV));
        float q1k = sAccH[0][nn][k] + sAccH[1][nn][k] +
                    sAccH[2][nn][k] + sAccH[3][nn][k];
        float q2k = sAccH[0][nn][32 + k] + sAccH[1][nn][32 + k] +
                    sAccH[2][nn][32 + k] + sAccH[3][nn][32 + k];
        float f = -0.5f * (q1k - 2.0f * sv * q2k + sv2 * q3[k]);
        ll = fmaf(P_, f, ll);
    }
    ll += __shfl_xor(ll, 1);
    ll += __shfl_xor(ll, 2);
    ll += __shfl_xor(ll, 4);
    float llacc = (j == 0 && valid) ? ll : 0.0f;

    if (valid) {
        size_t base = (size_t)n * 32 + j * 4;
        float2* op = (float2*)(outP + base);   // d_out P region only 8B-aligned
        op[0] = make_float2(pv[0], pv[1]);
        op[1] = make_float2(pv[2], pv[3]);

        // packed 128B records: [xl|P] src side, [xr|logP] dst side
        float* sr = srcRec + (size_t)n * 32;
        float* dr = dstRec + (size_t)n * 32;
        *(ushort4v*)&((unsigned short*)sr)[16 + j * 4] = pb;
        *(ushort4v*)&((unsigned short*)dr)[16 + j * 4] = lb;
        sr[j] = (sAccH[0][nn][64 + j] + sAccH[1][nn][64 + j] +
                 sAccH[2][nn][64 + j] + sAccH[3][nn][64 + j]) + bl[j];
        dr[j] = (sAccH[0][nn][72 + j] + sAccH[1][nn][72 + j] +
                 sAccH[2][nn][72 + j] + sAccH[3][nn][72 + j]) + br[j];
    }

    // ---- per-wave reduce -> one partial per wave (no LDS, no atomics) ----
    for (int off = 32; off; off >>= 1) llacc += __shfl_down(llacc, off);
    if (lane == 0) pll[blockIdx.x * 4 + wq] = llacc;
}

// ---------------- edge pass 1: gathers + contrib + single den atomic ---------
// (round-11 winner: 1 thread/edge, 12 x 16B loads over 2 packed cache lines)
__global__ __launch_bounds__(256, 4)
void edge1_kernel(const int* __restrict__ ei, const float* __restrict__ srcRec,
                  const float* __restrict__ dstRec, const float* __restrict__ att,
                  float* __restrict__ contrib, float* __restrict__ den) {
    int i = blockIdx.x * 256 + threadIdx.x;
    if (i >= E_EDGES) return;
    int s = ei[i];
    int d = ei[E_EDGES + i];
    const float4* sp = (const float4*)(srcRec + (size_t)s * 32);
    const float4* dp = (const float4*)(dstRec + (size_t)d * 32);
    float4 a0 = sp[0], a1 = sp[1];
    float4 b0 = dp[0], b1 = dp[1];
    const ushort8* pp = (const ushort8*)(sp + 2);
    const ushort8* lp = (const ushort8*)(dp + 2);
    ushort8 pa = pp[0], pb_ = pp[1], pc = pp[2], pd = pp[3];
    ushort8 la = lp[0], lb_ = lp[1], lc = lp[2], ld = lp[3];
    const float4* atp = (const float4*)att;
    float4 t0 = atp[0], t1 = atp[1];
    float at[8] = {t0.x, t0.y, t0.z, t0.w, t1.x, t1.y, t1.z, t1.w};
    float h[8] = {a0.x + b0.x, a0.y + b0.y, a0.z + b0.z, a0.w + b0.w,
                  a1.x + b1.x, a1.y + b1.y, a1.z + b1.z, a1.w + b1.w};
    float ev = 0.0f;
#pragma unroll
    for (int q = 0; q < 8; ++q) {
        float hv = h[q];
        hv = hv > 0.0f ? hv : 0.2f * hv;
        ev = fmaf(hv, at[q], ev);
    }
    float x = __expf(ev);
    atomicAdd(den + d, x);

    float dot = 0.0f;
#pragma unroll
    for (int r = 0; r < 8; ++r) {
        dot = fmaf(bf2f(pa[r]),  bf2f(la[r]),  dot);
        dot = fmaf(bf2f(pb_[r]), bf2f(lb_[r]), dot);
        dot = fmaf(bf2f(pc[r]),  bf2f(lc[r]),  dot);
        dot = fmaf(bf2f(pd[r]),  bf2f(ld[r]),  dot);
    }
    contrib[i] = x * dot;
}

// ---------------- edge pass 2 + finalize (last-block reduction) --------------
__global__ __launch_bounds__(256)
void edge2_final_kernel(const int* __restrict__ ei, const float* __restrict__ contrib,
                        const float* __restrict__ den, const float* __restrict__ pll,
                        float* __restrict__ pce, unsigned* __restrict__ ticket,
                        float* __restrict__ out) {
    const int t = threadIdx.x;
    const int base = (blockIdx.x * 256 + t) * 2;
    float ce = 0.0f;
    if (base < E_EDGES) {
        int2 dd = *(const int2*)&ei[E_EDGES + base];
        float2 cv = *(const float2*)&contrib[base];
        ce = cv.x / den[dd.x] + cv.y / den[dd.y];
    }
    for (int off = 32; off; off >>= 1) ce += __shfl_down(ce, off);
    __shared__ float sC[4];
    __shared__ int lastFlag;
    if ((t & 63) == 0) sC[t >> 6] = ce;
    __syncthreads();
    if (t == 0) {
        pce[blockIdx.x] = sC[0] + sC[1] + sC[2] + sC[3];
        __threadfence();
        unsigned old = atomicAdd(ticket, 1u);
        lastFlag = (old == NB_CE - 1);
    }
    __syncthreads();
    if (!lastFlag) return;
    __threadfence();   // acquire: see all blocks' pce stores

    float a = 0.0f, b = 0.0f;
    for (int i = t; i < NB_NODE * 4; i += 256) a += pll[i];
    for (int i = t; i < NB_CE; i += 256) b += pce[i];
    for (int off = 32; off; off >>= 1) {
        a += __shfl_down(a, off);
        b += __shfl_down(b, off);
    }
    __shared__ float sA[4], sB[4];
    if ((t & 63) == 0) { sA[t >> 6] = a; sB[t >> 6] = b; }
    __syncthreads();
    if (t == 0) {
        float ll = sA[0] + sA[1] + sA[2] + sA[3];
        float cesum = sB[0] + sB[1] + sB[2] + sB[3];
        out[0] = ll / (float)N_NODES;
        out[1] = -cesum / (float)N_NODES;
    }
}

extern "C" void kernel_launch(void* const* d_in, const int* in_sizes, int n_in,
                              void* d_out, int out_size, void* d_ws, size_t ws_size,
                              hipStream_t stream) {
    const float* X   = (const float*)d_in[0];
    const float* Mu  = (const float*)d_in[1];
    const float* Var = (const float*)d_in[2];
    const float* W   = (const float*)d_in[3];
    const float* S   = (const float*)d_in[4];
    const float* Wl  = (const float*)d_in[5];
    const float* bl  = (const float*)d_in[6];
    const float* Wr  = (const float*)d_in[7];
    const float* br  = (const float*)d_in[8];
    const float* att = (const float*)d_in[9];
    const int*   ei  = (const int*)d_in[10];
    float* out = (float*)d_out;
    float* ws  = (float*)d_ws;

    unsigned short* Tb     = (unsigned short*)(ws + OFF_T);
    float*          q3     = ws + OFF_Q3;
    float*          srcRec = ws + OFF_SRC;
    float*          dstRec = ws + OFF_DST;
    float*          contrib= ws + OFF_CON;
    float*          den    = ws + OFF_DEN;
    float*          pll    = ws + OFF_PLL;
    float*          pce    = ws + OFF_PCE;
    unsigned*       ticket = (unsigned*)(ws + OFF_TK);

    prep_kernel<<<(N_NODES + 255) / 256, 256, 0, stream>>>(Var, Mu, Wl, Wr, Tb, den, q3, ticket);
    node_kernel<<<NB_NODE, 256, 0, stream>>>(X, W, S, bl, br, Tb, q3,
                                             out + 2, srcRec, dstRec, pll);
    edge1_kernel<<<NB_E1, 256, 0, stream>>>(ei, srcRec, dstRec, att, contrib, den);
    edge2_final_kernel<<<NB_CE, 256, 0, stream>>>(ei, contrib, den, pll, pce, ticket, out);
}

// Round 14
// 76.839 us; speedup vs baseline: 1.1800x; 1.1800x over previous
//
#include <hip/hip_runtime.h>
#include <hip/hip_bf16.h>
#include <math.h>

#define N_NODES 50000
#define K_COMP  32
#define G_DIM   512
#define E_EDGES 400000
#define OUT_DIM 8
#define EPSV    1e-8f

#define NPB 32                                  // nodes per node-kernel block
#define NB_NODE ((N_NODES + NPB - 1) / NPB)     // 1563
#define NB_E1   ((E_EDGES + 255) / 256)         // 1563 (1 edge/thread)
#define NB_CE   ((E_EDGES / 2 + 255) / 256)     // 782  (2 edges/thread)

typedef __attribute__((ext_vector_type(8))) short short8;
typedef __attribute__((ext_vector_type(8))) unsigned short ushort8;
typedef __attribute__((ext_vector_type(4))) unsigned short ushort4v;
typedef __attribute__((ext_vector_type(4))) float f32x4;

// ---------------- ws layout (float-indexed offsets) ----------------
// srcRec[n]: 32 floats = [0:8) xl f32 | [8:24) P bf16x32 | pad   (128B aligned)
// dstRec[n]: 32 floats = [0:8) xr f32 | [8:24) logP bf16x32 | pad
static const size_t OFF_T    = 0;                               // bf16 table 80*512 ushort (fragment-major)
static const size_t OFF_Q3   = OFF_T + 80 * 512;
static const size_t OFF_SRC  = OFF_Q3 + 64;                     // N*32 floats, 128B-aligned
static const size_t OFF_DST  = OFF_SRC + (size_t)N_NODES * 32;
static const size_t OFF_CON  = OFF_DST + (size_t)N_NODES * 32;  // E floats
static const size_t OFF_DEN  = OFF_CON + E_EDGES;               // N floats
static const size_t OFF_PLL  = OFF_DEN + N_NODES;               // NB_NODE*4 wave partials
static const size_t OFF_PCE  = OFF_PLL + 8192;                  // NB_CE partials

__device__ __forceinline__ unsigned short f2bf(float f) {
    __hip_bfloat16 h = __float2bfloat16(f);
    return *(unsigned short*)&h;
}
__device__ __forceinline__ float bf2f(unsigned short u) {
    unsigned v = ((unsigned)u) << 16;
    return __uint_as_float(v);
}

// ---------------- prep: fragment-major bf16 table + q3 + zero den ----------
__global__ __launch_bounds__(256)
void prep_kernel(const float* __restrict__ Var, const float* __restrict__ Mu,
                 const float* __restrict__ Wl, const float* __restrict__ Wr,
                 unsigned short* __restrict__ Tb, float* __restrict__ den,
                 float* __restrict__ q3) {
    int idx = blockIdx.x * 256 + threadIdx.x;
    if (idx < 80 * 512) {
        int r = idx >> 9;        // logical out-row 0..79
        int g = idx & 511;       // logical k 0..511
        float v;
        if (r < 32)      v = 1.0f / Var[r * 512 + g];
        else if (r < 64) { int k = r - 32; v = Mu[k * 512 + g] / Var[k * 512 + g]; }
        else if (r < 72) { int o = r - 64; v = Wl[g * 8 + o]; }
        else             { int o = r - 72; v = Wr[g * 8 + o]; }
        int dest = ((g >> 5) * 5 + (r >> 4)) * 512 + (r & 15) * 32 + (((g & 31) >> 3) << 3) + (g & 7);
        Tb[dest] = f2bf(v);
    }
    if (idx < N_NODES) den[idx] = 0.0f;

    if (blockIdx.x < 32) {
        int k = blockIdx.x;
        int t = threadIdx.x;
        float s = 0.0f;
        for (int g = t; g < 512; g += 256) {
            float mu = Mu[k * 512 + g];
            s += mu * mu / Var[k * 512 + g];
        }
        for (int off = 32; off; off >>= 1) s += __shfl_down(s, off);
        __shared__ float sQ[4];
        if ((t & 63) == 0) sQ[t >> 6] = s;
        __syncthreads();
        if (t == 0) q3[k] = sQ[0] + sQ[1] + sQ[2] + sQ[3];
    }
}

// ---------------- fused node kernel (MFMA, k-split x4, 2 node-tiles/wave) ----
__global__ __launch_bounds__(256, 4)
void node_kernel(const float* __restrict__ X, const float* __restrict__ W,
                 const float* __restrict__ S, const float* __restrict__ bl,
                 const float* __restrict__ br, const unsigned short* __restrict__ Tb,
                 const float* __restrict__ q3, float* __restrict__ outP,
                 float* __restrict__ srcRec, float* __restrict__ dstRec,
                 float* __restrict__ pll) {
    __shared__ float sAccH[4][NPB][80];   // 40960 B exactly

    const int t = threadIdx.x;
    const int lane = t & 63;
    const int wq = t >> 6;        // K-quarter 0..3
    const int col = lane & 15;
    const int kg  = lane >> 4;    // 0..3

    const int n0 = blockIdx.x * NPB;
    int nodeA = n0 + col;
    int nodeB = n0 + 16 + col;
    if (nodeA >= N_NODES) nodeA = N_NODES - 1;   // tail clamp (loads only)
    if (nodeB >= N_NODES) nodeB = N_NODES - 1;
    const float* xrowA = X + (size_t)nodeA * 512 + wq * 128 + kg * 8;
    const float* xrowB = X + (size_t)nodeB * 512 + wq * 128 + kg * 8;

    f32x4 accA[5], accB[5];
#pragma unroll
    for (int i = 0; i < 5; ++i) {
        accA[i] = (f32x4){0.f, 0.f, 0.f, 0.f};
        accB[i] = (f32x4){0.f, 0.f, 0.f, 0.f};
    }

#pragma unroll
    for (int it = 0; it < 4; ++it) {
        const unsigned short* bbase =
            Tb + (size_t)(wq * 4 + it) * 5 * 512 + col * 32 + kg * 8;
        short8 b0 = *(const short8*)(bbase);
        short8 b1 = *(const short8*)(bbase + 512);
        short8 b2 = *(const short8*)(bbase + 1024);
        short8 b3 = *(const short8*)(bbase + 1536);
        short8 b4 = *(const short8*)(bbase + 2048);

        float4 va0 = *(const float4*)(xrowA + it * 32);
        float4 va1 = *(const float4*)(xrowA + it * 32 + 4);
        float4 vb0 = *(const float4*)(xrowB + it * 32);
        float4 vb1 = *(const float4*)(xrowB + it * 32 + 4);

        short8 axA, axA2, axB, axB2;
        axA[0] = (short)f2bf(va0.x); axA[1] = (short)f2bf(va0.y);
        axA[2] = (short)f2bf(va0.z); axA[3] = (short)f2bf(va0.w);
        axA[4] = (short)f2bf(va1.x); axA[5] = (short)f2bf(va1.y);
        axA[6] = (short)f2bf(va1.z); axA[7] = (short)f2bf(va1.w);
        axA2[0] = (short)f2bf(va0.x * va0.x); axA2[1] = (short)f2bf(va0.y * va0.y);
        axA2[2] = (short)f2bf(va0.z * va0.z); axA2[3] = (short)f2bf(va0.w * va0.w);
        axA2[4] = (short)f2bf(va1.x * va1.x); axA2[5] = (short)f2bf(va1.y * va1.y);
        axA2[6] = (short)f2bf(va1.z * va1.z); axA2[7] = (short)f2bf(va1.w * va1.w);
        axB[0] = (short)f2bf(vb0.x); axB[1] = (short)f2bf(vb0.y);
        axB[2] = (short)f2bf(vb0.z); axB[3] = (short)f2bf(vb0.w);
        axB[4] = (short)f2bf(vb1.x); axB[5] = (short)f2bf(vb1.y);
        axB[6] = (short)f2bf(vb1.z); axB[7] = (short)f2bf(vb1.w);
        axB2[0] = (short)f2bf(vb0.x * vb0.x); axB2[1] = (short)f2bf(vb0.y * vb0.y);
        axB2[2] = (short)f2bf(vb0.z * vb0.z); axB2[3] = (short)f2bf(vb0.w * vb0.w);
        axB2[4] = (short)f2bf(vb1.x * vb1.x); axB2[5] = (short)f2bf(vb1.y * vb1.y);
        axB2[6] = (short)f2bf(vb1.z * vb1.z); axB2[7] = (short)f2bf(vb1.w * vb1.w);

        accA[0] = __builtin_amdgcn_mfma_f32_16x16x32_bf16(axA2, b0, accA[0], 0, 0, 0);
        accB[0] = __builtin_amdgcn_mfma_f32_16x16x32_bf16(axB2, b0, accB[0], 0, 0, 0);
        accA[1] = __builtin_amdgcn_mfma_f32_16x16x32_bf16(axA2, b1, accA[1], 0, 0, 0);
        accB[1] = __builtin_amdgcn_mfma_f32_16x16x32_bf16(axB2, b1, accB[1], 0, 0, 0);
        accA[2] = __builtin_amdgcn_mfma_f32_16x16x32_bf16(axA,  b2, accA[2], 0, 0, 0);
        accB[2] = __builtin_amdgcn_mfma_f32_16x16x32_bf16(axB,  b2, accB[2], 0, 0, 0);
        accA[3] = __builtin_amdgcn_mfma_f32_16x16x32_bf16(axA,  b3, accA[3], 0, 0, 0);
        accB[3] = __builtin_amdgcn_mfma_f32_16x16x32_bf16(axB,  b3, accB[3], 0, 0, 0);
        accA[4] = __builtin_amdgcn_mfma_f32_16x16x32_bf16(axA,  b4, accA[4], 0, 0, 0);
        accB[4] = __builtin_amdgcn_mfma_f32_16x16x32_bf16(axB,  b4, accB[4], 0, 0, 0);
    }

    // ---- scatter partial accumulators (per K-quarter, both tiles) ----
#pragma unroll
    for (int ot = 0; ot < 5; ++ot)
#pragma unroll
        for (int r = 0; r < 4; ++r) {
            sAccH[wq][kg * 4 + r][ot * 16 + col]      = accA[ot][r];
            sAccH[wq][16 + kg * 4 + r][ot * 16 + col] = accB[ot][r];
        }
    __syncthreads();

    // ---- epilogue: 8 threads per node; thread handles k = j*4 .. j*4+3 ----
    const int nn = t >> 3;        // 0..31
    const int j = t & 7;          // 0..7
    const int n = n0 + nn;
    const bool valid = n < N_NODES;
    const int nc = valid ? n : N_NODES - 1;

    float sv = S[nc];
    float sv2 = sv * sv;
    float4 wv4 = *(const float4*)(W + (size_t)nc * 32 + j * 4);
    float w[4] = {wv4.x, wv4.y, wv4.z, wv4.w};
    float wm = fmaxf(fmaxf(w[0], w[1]), fmaxf(w[2], w[3]));
    wm = fmaxf(wm, __shfl_xor(wm, 1));
    wm = fmaxf(wm, __shfl_xor(wm, 2));
    wm = fmaxf(wm, __shfl_xor(wm, 4));
    float p[4], ps = 0.0f;
#pragma unroll
    for (int i = 0; i < 4; ++i) { p[i] = __expf(w[i] - wm); ps += p[i]; }
    ps += __shfl_xor(ps, 1);
    ps += __shfl_xor(ps, 2);
    ps += __shfl_xor(ps, 4);
    float inv = 1.0f / ps;

    float pv[4];
    ushort4v pb, lb;
    float ll = 0.0f;
#pragma unroll
    for (int i = 0; i < 4; ++i) {
        int k = j * 4 + i;
        float P_ = p[i] * inv;
        pv[i] = P_;
        pb[i] = f2bf(P_);
        lb[i] = f2bf(__logf(P_ + EPSV));
        float q1k = sAccH[0][nn][k] + sAccH[1][nn][k] +
                    sAccH[2][nn][k] + sAccH[3][nn][k];
        float q2k = sAccH[0][nn][32 + k] + sAccH[1][nn][32 + k] +
                    sAccH[2][nn][32 + k] + sAccH[3][nn][32 + k];
        float f = -0.5f * (q1k - 2.0f * sv * q2k + sv2 * q3[k]);
        ll = fmaf(P_, f, ll);
    }
    ll += __shfl_xor(ll, 1);
    ll += __shfl_xor(ll, 2);
    ll += __shfl_xor(ll, 4);
    float llacc = (j == 0 && valid) ? ll : 0.0f;

    if (valid) {
        size_t base = (size_t)n * 32 + j * 4;
        float2* op = (float2*)(outP + base);   // d_out P region only 8B-aligned
        op[0] = make_float2(pv[0], pv[1]);
        op[1] = make_float2(pv[2], pv[3]);

        // packed 128B records: [xl|P] src side, [xr|logP] dst side
        float* sr = srcRec + (size_t)n * 32;
        float* dr = dstRec + (size_t)n * 32;
        *(ushort4v*)&((unsigned short*)sr)[16 + j * 4] = pb;
        *(ushort4v*)&((unsigned short*)dr)[16 + j * 4] = lb;
        sr[j] = (sAccH[0][nn][64 + j] + sAccH[1][nn][64 + j] +
                 sAccH[2][nn][64 + j] + sAccH[3][nn][64 + j]) + bl[j];
        dr[j] = (sAccH[0][nn][72 + j] + sAccH[1][nn][72 + j] +
                 sAccH[2][nn][72 + j] + sAccH[3][nn][72 + j]) + br[j];
    }

    // ---- per-wave reduce -> one partial per wave (no LDS, no atomics) ----
    for (int off = 32; off; off >>= 1) llacc += __shfl_down(llacc, off);
    if (lane == 0) pll[blockIdx.x * 4 + wq] = llacc;
}

// ---------------- edge pass 1: gathers + contrib + single den atomic ---------
// (1 thread/edge, 12 x 16B loads over 2 packed cache lines)
__global__ __launch_bounds__(256, 4)
void edge1_kernel(const int* __restrict__ ei, const float* __restrict__ srcRec,
                  const float* __restrict__ dstRec, const float* __restrict__ att,
                  float* __restrict__ contrib, float* __restrict__ den) {
    int i = blockIdx.x * 256 + threadIdx.x;
    if (i >= E_EDGES) return;
    int s = ei[i];
    int d = ei[E_EDGES + i];
    const float4* sp = (const float4*)(srcRec + (size_t)s * 32);
    const float4* dp = (const float4*)(dstRec + (size_t)d * 32);
    float4 a0 = sp[0], a1 = sp[1];
    float4 b0 = dp[0], b1 = dp[1];
    const ushort8* pp = (const ushort8*)(sp + 2);
    const ushort8* lp = (const ushort8*)(dp + 2);
    ushort8 pa = pp[0], pb_ = pp[1], pc = pp[2], pd = pp[3];
    ushort8 la = lp[0], lb_ = lp[1], lc = lp[2], ld = lp[3];
    const float4* atp = (const float4*)att;
    float4 t0 = atp[0], t1 = atp[1];
    float at[8] = {t0.x, t0.y, t0.z, t0.w, t1.x, t1.y, t1.z, t1.w};
    float h[8] = {a0.x + b0.x, a0.y + b0.y, a0.z + b0.z, a0.w + b0.w,
                  a1.x + b1.x, a1.y + b1.y, a1.z + b1.z, a1.w + b1.w};
    float ev = 0.0f;
#pragma unroll
    for (int q = 0; q < 8; ++q) {
        float hv = h[q];
        hv = hv > 0.0f ? hv : 0.2f * hv;
        ev = fmaf(hv, at[q], ev);
    }
    float x = __expf(ev);
    atomicAdd(den + d, x);

    float dot = 0.0f;
#pragma unroll
    for (int r = 0; r < 8; ++r) {
        dot = fmaf(bf2f(pa[r]),  bf2f(la[r]),  dot);
        dot = fmaf(bf2f(pb_[r]), bf2f(lb_[r]), dot);
        dot = fmaf(bf2f(pc[r]),  bf2f(lc[r]),  dot);
        dot = fmaf(bf2f(pd[r]),  bf2f(ld[r]),  dot);
    }
    contrib[i] = x * dot;
}

// ---------------- edge pass 2: ce = sum contrib/den[dst] (streaming) ---------
__global__ __launch_bounds__(256, 4)
void edge2_kernel(const int* __restrict__ ei, const float* __restrict__ contrib,
                  const float* __restrict__ den, float* __restrict__ pce) {
    const int t = threadIdx.x;
    const int base = (blockIdx.x * 256 + t) * 2;
    float ce = 0.0f;
    if (base < E_EDGES) {
        int2 dd = *(const int2*)&ei[E_EDGES + base];
        float2 cv = *(const float2*)&contrib[base];
        ce = cv.x / den[dd.x] + cv.y / den[dd.y];
    }
    for (int off = 32; off; off >>= 1) ce += __shfl_down(ce, off);
    __shared__ float sC[4];
    if ((t & 63) == 0) sC[t >> 6] = ce;
    __syncthreads();
    if (t == 0) pce[blockIdx.x] = sC[0] + sC[1] + sC[2] + sC[3];
}

// ---------------- finalize: sum partials ----------------
__global__ __launch_bounds__(256)
void finalize_kernel(const float* __restrict__ pll, const float* __restrict__ pce,
                     float* __restrict__ out) {
    const int t = threadIdx.x;
    float a = 0.0f, b = 0.0f;
    for (int i = t; i < NB_NODE * 4; i += 256) a += pll[i];
    for (int i = t; i < NB_CE; i += 256) b += pce[i];
    for (int off = 32; off; off >>= 1) {
        a += __shfl_down(a, off);
        b += __shfl_down(b, off);
    }
    __shared__ float sA[4], sB[4];
    if ((t & 63) == 0) { sA[t >> 6] = a; sB[t >> 6] = b; }
    __syncthreads();
    if (t == 0) {
        float ll = sA[0] + sA[1] + sA[2] + sA[3];
        float ce = sB[0] + sB[1] + sB[2] + sB[3];
        out[0] = ll / (float)N_NODES;
        out[1] = -ce / (float)N_NODES;
    }
}

extern "C" void kernel_launch(void* const* d_in, const int* in_sizes, int n_in,
                              void* d_out, int out_size, void* d_ws, size_t ws_size,
                              hipStream_t stream) {
    const float* X   = (const float*)d_in[0];
    const float* Mu  = (const float*)d_in[1];
    const float* Var = (const float*)d_in[2];
    const float* W   = (const float*)d_in[3];
    const float* S   = (const float*)d_in[4];
    const float* Wl  = (const float*)d_in[5];
    const float* bl  = (const float*)d_in[6];
    const float* Wr  = (const float*)d_in[7];
    const float* br  = (const float*)d_in[8];
    const float* att = (const float*)d_in[9];
    const int*   ei  = (const int*)d_in[10];
    float* out = (float*)d_out;
    float* ws  = (float*)d_ws;

    unsigned short* Tb     = (unsigned short*)(ws + OFF_T);
    float*          q3     = ws + OFF_Q3;
    float*          srcRec = ws + OFF_SRC;
    float*          dstRec = ws + OFF_DST;
    float*          contrib= ws + OFF_CON;
    float*          den    = ws + OFF_DEN;
    float*          pll    = ws + OFF_PLL;
    float*          pce    = ws + OFF_PCE;

    prep_kernel<<<(N_NODES + 255) / 256, 256, 0, stream>>>(Var, Mu, Wl, Wr, Tb, den, q3);
    node_kernel<<<NB_NODE, 256, 0, stream>>>(X, W, S, bl, br, Tb, q3,
                                             out + 2, srcRec, dstRec, pll);
    edge1_kernel<<<NB_E1, 256, 0, stream>>>(ei, srcRec, dstRec, att, contrib, den);
    edge2_kernel<<<NB_CE, 256, 0, stream>>>(ei, contrib, den, pce);
    finalize_kernel<<<1, 256, 0, stream>>>(pll, pce, out);
}

// Round 15
// 76.607 us; speedup vs baseline: 1.1835x; 1.0030x over previous
//
#include <hip/hip_runtime.h>
#include <hip/hip_bf16.h>
#include <hip/hip_fp8.h>
#include <math.h>

#define N_NODES 50000
#define K_COMP  32
#define G_DIM   512
#define E_EDGES 400000
#define OUT_DIM 8
#define EPSV    1e-8f

#define NPB 32                                  // nodes per node-kernel block
#define NB_NODE ((N_NODES + NPB - 1) / NPB)     // 1563
#define NB_E1   ((E_EDGES + 255) / 256)         // 1563 (1 edge/thread)
#define NB_CE   ((E_EDGES / 2 + 255) / 256)     // 782  (2 edges/thread)

typedef __attribute__((ext_vector_type(8))) short short8;
typedef __attribute__((ext_vector_type(4))) float f32x4;

// ---------------- ws layout (float-indexed offsets) ----------------
// srcRec[n]: 16 floats = 64B: [0:8) xl f32 | [8:16) P fp8e4m3 x32
// dstRec[n]: 16 floats = 64B: [0:8) xr f32 | [8:16) logP fp8e4m3 x32
static const size_t OFF_T    = 0;                               // bf16 table 80*512 ushort (fragment-major)
static const size_t OFF_Q3   = OFF_T + 80 * 512;
static const size_t OFF_SRC  = OFF_Q3 + 64;                     // N*16 floats, 64B-aligned
static const size_t OFF_DST  = OFF_SRC + (size_t)N_NODES * 16;
static const size_t OFF_CON  = OFF_DST + (size_t)N_NODES * 16;  // E floats
static const size_t OFF_DEN  = OFF_CON + E_EDGES;               // N floats
static const size_t OFF_PLL  = OFF_DEN + N_NODES;               // NB_NODE*4 wave partials
static const size_t OFF_PCE  = OFF_PLL + 8192;                  // NB_CE partials

__device__ __forceinline__ unsigned short f2bf(float f) {
    __hip_bfloat16 h = __float2bfloat16(f);
    return *(unsigned short*)&h;
}
__device__ __forceinline__ float f8f(unsigned byte) {
    __hip_fp8_e4m3 v;
    v.__x = (__hip_fp8_storage_t)byte;
    return (float)v;
}
__device__ __forceinline__ unsigned pack4f8(float a, float b, float c, float d) {
    __hip_fp8_e4m3 fa(a), fb(b), fc(c), fd(d);
    return (unsigned)fa.__x | ((unsigned)fb.__x << 8) |
           ((unsigned)fc.__x << 16) | ((unsigned)fd.__x << 24);
}

// ---------------- prep: fragment-major bf16 table + q3 + zero den ----------
__global__ __launch_bounds__(256)
void prep_kernel(const float* __restrict__ Var, const float* __restrict__ Mu,
                 const float* __restrict__ Wl, const float* __restrict__ Wr,
                 unsigned short* __restrict__ Tb, float* __restrict__ den,
                 float* __restrict__ q3) {
    int idx = blockIdx.x * 256 + threadIdx.x;
    if (idx < 80 * 512) {
        int r = idx >> 9;        // logical out-row 0..79
        int g = idx & 511;       // logical k 0..511
        float v;
        if (r < 32)      v = 1.0f / Var[r * 512 + g];
        else if (r < 64) { int k = r - 32; v = Mu[k * 512 + g] / Var[k * 512 + g]; }
        else if (r < 72) { int o = r - 64; v = Wl[g * 8 + o]; }
        else             { int o = r - 72; v = Wr[g * 8 + o]; }
        int dest = ((g >> 5) * 5 + (r >> 4)) * 512 + (r & 15) * 32 + (((g & 31) >> 3) << 3) + (g & 7);
        Tb[dest] = f2bf(v);
    }
    if (idx < N_NODES) den[idx] = 0.0f;

    if (blockIdx.x < 32) {
        int k = blockIdx.x;
        int t = threadIdx.x;
        float s = 0.0f;
        for (int g = t; g < 512; g += 256) {
            float mu = Mu[k * 512 + g];
            s += mu * mu / Var[k * 512 + g];
        }
        for (int off = 32; off; off >>= 1) s += __shfl_down(s, off);
        __shared__ float sQ[4];
        if ((t & 63) == 0) sQ[t >> 6] = s;
        __syncthreads();
        if (t == 0) q3[k] = sQ[0] + sQ[1] + sQ[2] + sQ[3];
    }
}

// ---------------- fused node kernel (MFMA, k-split x4, 2 node-tiles/wave) ----
__global__ __launch_bounds__(256, 4)
void node_kernel(const float* __restrict__ X, const float* __restrict__ W,
                 const float* __restrict__ S, const float* __restrict__ bl,
                 const float* __restrict__ br, const unsigned short* __restrict__ Tb,
                 const float* __restrict__ q3, float* __restrict__ outP,
                 float* __restrict__ srcRec, float* __restrict__ dstRec,
                 float* __restrict__ pll) {
    __shared__ float sAccH[4][NPB][80];   // 40960 B exactly

    const int t = threadIdx.x;
    const int lane = t & 63;
    const int wq = t >> 6;        // K-quarter 0..3
    const int col = lane & 15;
    const int kg  = lane >> 4;    // 0..3

    const int n0 = blockIdx.x * NPB;
    int nodeA = n0 + col;
    int nodeB = n0 + 16 + col;
    if (nodeA >= N_NODES) nodeA = N_NODES - 1;   // tail clamp (loads only)
    if (nodeB >= N_NODES) nodeB = N_NODES - 1;
    const float* xrowA = X + (size_t)nodeA * 512 + wq * 128 + kg * 8;
    const float* xrowB = X + (size_t)nodeB * 512 + wq * 128 + kg * 8;

    f32x4 accA[5], accB[5];
#pragma unroll
    for (int i = 0; i < 5; ++i) {
        accA[i] = (f32x4){0.f, 0.f, 0.f, 0.f};
        accB[i] = (f32x4){0.f, 0.f, 0.f, 0.f};
    }

#pragma unroll
    for (int it = 0; it < 4; ++it) {
        const unsigned short* bbase =
            Tb + (size_t)(wq * 4 + it) * 5 * 512 + col * 32 + kg * 8;
        short8 b0 = *(const short8*)(bbase);
        short8 b1 = *(const short8*)(bbase + 512);
        short8 b2 = *(const short8*)(bbase + 1024);
        short8 b3 = *(const short8*)(bbase + 1536);
        short8 b4 = *(const short8*)(bbase + 2048);

        float4 va0 = *(const float4*)(xrowA + it * 32);
        float4 va1 = *(const float4*)(xrowA + it * 32 + 4);
        float4 vb0 = *(const float4*)(xrowB + it * 32);
        float4 vb1 = *(const float4*)(xrowB + it * 32 + 4);

        short8 axA, axA2, axB, axB2;
        axA[0] = (short)f2bf(va0.x); axA[1] = (short)f2bf(va0.y);
        axA[2] = (short)f2bf(va0.z); axA[3] = (short)f2bf(va0.w);
        axA[4] = (short)f2bf(va1.x); axA[5] = (short)f2bf(va1.y);
        axA[6] = (short)f2bf(va1.z); axA[7] = (short)f2bf(va1.w);
        axA2[0] = (short)f2bf(va0.x * va0.x); axA2[1] = (short)f2bf(va0.y * va0.y);
        axA2[2] = (short)f2bf(va0.z * va0.z); axA2[3] = (short)f2bf(va0.w * va0.w);
        axA2[4] = (short)f2bf(va1.x * va1.x); axA2[5] = (short)f2bf(va1.y * va1.y);
        axA2[6] = (short)f2bf(va1.z * va1.z); axA2[7] = (short)f2bf(va1.w * va1.w);
        axB[0] = (short)f2bf(vb0.x); axB[1] = (short)f2bf(vb0.y);
        axB[2] = (short)f2bf(vb0.z); axB[3] = (short)f2bf(vb0.w);
        axB[4] = (short)f2bf(vb1.x); axB[5] = (short)f2bf(vb1.y);
        axB[6] = (short)f2bf(vb1.z); axB[7] = (short)f2bf(vb1.w);
        axB2[0] = (short)f2bf(vb0.x * vb0.x); axB2[1] = (short)f2bf(vb0.y * vb0.y);
        axB2[2] = (short)f2bf(vb0.z * vb0.z); axB2[3] = (short)f2bf(vb0.w * vb0.w);
        axB2[4] = (short)f2bf(vb1.x * vb1.x); axB2[5] = (short)f2bf(vb1.y * vb1.y);
        axB2[6] = (short)f2bf(vb1.z * vb1.z); axB2[7] = (short)f2bf(vb1.w * vb1.w);

        accA[0] = __builtin_amdgcn_mfma_f32_16x16x32_bf16(axA2, b0, accA[0], 0, 0, 0);
        accB[0] = __builtin_amdgcn_mfma_f32_16x16x32_bf16(axB2, b0, accB[0], 0, 0, 0);
        accA[1] = __builtin_amdgcn_mfma_f32_16x16x32_bf16(axA2, b1, accA[1], 0, 0, 0);
        accB[1] = __builtin_amdgcn_mfma_f32_16x16x32_bf16(axB2, b1, accB[1], 0, 0, 0);
        accA[2] = __builtin_amdgcn_mfma_f32_16x16x32_bf16(axA,  b2, accA[2], 0, 0, 0);
        accB[2] = __builtin_amdgcn_mfma_f32_16x16x32_bf16(axB,  b2, accB[2], 0, 0, 0);
        accA[3] = __builtin_amdgcn_mfma_f32_16x16x32_bf16(axA,  b3, accA[3], 0, 0, 0);
        accB[3] = __builtin_amdgcn_mfma_f32_16x16x32_bf16(axB,  b3, accB[3], 0, 0, 0);
        accA[4] = __builtin_amdgcn_mfma_f32_16x16x32_bf16(axA,  b4, accA[4], 0, 0, 0);
        accB[4] = __builtin_amdgcn_mfma_f32_16x16x32_bf16(axB,  b4, accB[4], 0, 0, 0);
    }

    // ---- scatter partial accumulators (per K-quarter, both tiles) ----
#pragma unroll
    for (int ot = 0; ot < 5; ++ot)
#pragma unroll
        for (int r = 0; r < 4; ++r) {
            sAccH[wq][kg * 4 + r][ot * 16 + col]      = accA[ot][r];
            sAccH[wq][16 + kg * 4 + r][ot * 16 + col] = accB[ot][r];
        }
    __syncthreads();

    // ---- epilogue: 8 threads per node; thread handles k = j*4 .. j*4+3 ----
    const int nn = t >> 3;        // 0..31
    const int j = t & 7;          // 0..7
    const int n = n0 + nn;
    const bool valid = n < N_NODES;
    const int nc = valid ? n : N_NODES - 1;

    float sv = S[nc];
    float sv2 = sv * sv;
    float4 wv4 = *(const float4*)(W + (size_t)nc * 32 + j * 4);
    float w[4] = {wv4.x, wv4.y, wv4.z, wv4.w};
    float wm = fmaxf(fmaxf(w[0], w[1]), fmaxf(w[2], w[3]));
    wm = fmaxf(wm, __shfl_xor(wm, 1));
    wm = fmaxf(wm, __shfl_xor(wm, 2));
    wm = fmaxf(wm, __shfl_xor(wm, 4));
    float p[4], ps = 0.0f;
#pragma unroll
    for (int i = 0; i < 4; ++i) { p[i] = __expf(w[i] - wm); ps += p[i]; }
    ps += __shfl_xor(ps, 1);
    ps += __shfl_xor(ps, 2);
    ps += __shfl_xor(ps, 4);
    float inv = 1.0f / ps;

    float pv[4], lg[4];
    float ll = 0.0f;
#pragma unroll
    for (int i = 0; i < 4; ++i) {
        int k = j * 4 + i;
        float P_ = p[i] * inv;
        pv[i] = P_;
        lg[i] = __logf(P_ + EPSV);
        float q1k = sAccH[0][nn][k] + sAccH[1][nn][k] +
                    sAccH[2][nn][k] + sAccH[3][nn][k];
        float q2k = sAccH[0][nn][32 + k] + sAccH[1][nn][32 + k] +
                    sAccH[2][nn][32 + k] + sAccH[3][nn][32 + k];
        float f = -0.5f * (q1k - 2.0f * sv * q2k + sv2 * q3[k]);
        ll = fmaf(P_, f, ll);
    }
    ll += __shfl_xor(ll, 1);
    ll += __shfl_xor(ll, 2);
    ll += __shfl_xor(ll, 4);
    float llacc = (j == 0 && valid) ? ll : 0.0f;

    if (valid) {
        size_t base = (size_t)n * 32 + j * 4;
        float2* op = (float2*)(outP + base);   // d_out P region only 8B-aligned
        op[0] = make_float2(pv[0], pv[1]);
        op[1] = make_float2(pv[2], pv[3]);

        // packed 64B records: [xl f32 | P fp8] src side, [xr f32 | logP fp8] dst
        float* sr = srcRec + (size_t)n * 16;
        float* dr = dstRec + (size_t)n * 16;
        ((unsigned*)sr)[8 + j] = pack4f8(pv[0], pv[1], pv[2], pv[3]);
        ((unsigned*)dr)[8 + j] = pack4f8(lg[0], lg[1], lg[2], lg[3]);
        sr[j] = (sAccH[0][nn][64 + j] + sAccH[1][nn][64 + j] +
                 sAccH[2][nn][64 + j] + sAccH[3][nn][64 + j]) + bl[j];
        dr[j] = (sAccH[0][nn][72 + j] + sAccH[1][nn][72 + j] +
                 sAccH[2][nn][72 + j] + sAccH[3][nn][72 + j]) + br[j];
    }

    // ---- per-wave reduce -> one partial per wave (no LDS, no atomics) ----
    for (int off = 32; off; off >>= 1) llacc += __shfl_down(llacc, off);
    if (lane == 0) pll[blockIdx.x * 4 + wq] = llacc;
}

// ---------------- edge pass 1: gathers + contrib + single den atomic ---------
// 64B records: per edge only 10 vmem instructions (2 ei + 4 src + 4 dst).
__global__ __launch_bounds__(256, 4)
void edge1_kernel(const int* __restrict__ ei, const float* __restrict__ srcRec,
                  const float* __restrict__ dstRec, const float* __restrict__ att,
                  float* __restrict__ contrib, float* __restrict__ den) {
    int i = blockIdx.x * 256 + threadIdx.x;
    if (i >= E_EDGES) return;
    int s = ei[i];
    int d = ei[E_EDGES + i];
    const float4* sp = (const float4*)(srcRec + (size_t)s * 16);
    const float4* dp = (const float4*)(dstRec + (size_t)d * 16);
    float4 a0 = sp[0], a1 = sp[1];
    float4 b0 = dp[0], b1 = dp[1];
    uint4 pq0 = ((const uint4*)sp)[2];   // P fp8 [0:16)
    uint4 pq1 = ((const uint4*)sp)[3];   // P fp8 [16:32)
    uint4 lq0 = ((const uint4*)dp)[2];   // logP fp8 [0:16)
    uint4 lq1 = ((const uint4*)dp)[3];   // logP fp8 [16:32)

    const float4* atp = (const float4*)att;
    float4 t0 = atp[0], t1 = atp[1];
    float at[8] = {t0.x, t0.y, t0.z, t0.w, t1.x, t1.y, t1.z, t1.w};
    float h[8] = {a0.x + b0.x, a0.y + b0.y, a0.z + b0.z, a0.w + b0.w,
                  a1.x + b1.x, a1.y + b1.y, a1.z + b1.z, a1.w + b1.w};
    float ev = 0.0f;
#pragma unroll
    for (int q = 0; q < 8; ++q) {
        float hv = h[q];
        hv = hv > 0.0f ? hv : 0.2f * hv;
        ev = fmaf(hv, at[q], ev);
    }
    float x = __expf(ev);
    atomicAdd(den + d, x);

    unsigned pw[8] = {pq0.x, pq0.y, pq0.z, pq0.w, pq1.x, pq1.y, pq1.z, pq1.w};
    unsigned lw[8] = {lq0.x, lq0.y, lq0.z, lq0.w, lq1.x, lq1.y, lq1.z, lq1.w};
    float dot = 0.0f;
#pragma unroll
    for (int q = 0; q < 8; ++q) {
        unsigned pu = pw[q], lu = lw[q];
        dot = fmaf(f8f(pu & 0xff),         f8f(lu & 0xff),         dot);
        dot = fmaf(f8f((pu >> 8) & 0xff),  f8f((lu >> 8) & 0xff),  dot);
        dot = fmaf(f8f((pu >> 16) & 0xff), f8f((lu >> 16) & 0xff), dot);
        dot = fmaf(f8f(pu >> 24),          f8f(lu >> 24),          dot);
    }
    contrib[i] = x * dot;
}

// ---------------- edge pass 2: ce = sum contrib/den[dst] (streaming) ---------
__global__ __launch_bounds__(256, 4)
void edge2_kernel(const int* __restrict__ ei, const float* __restrict__ contrib,
                  const float* __restrict__ den, float* __restrict__ pce) {
    const int t = threadIdx.x;
    const int base = (blockIdx.x * 256 + t) * 2;
    float ce = 0.0f;
    if (base < E_EDGES) {
        int2 dd = *(const int2*)&ei[E_EDGES + base];
        float2 cv = *(const float2*)&contrib[base];
        ce = cv.x / den[dd.x] + cv.y / den[dd.y];
    }
    for (int off = 32; off; off >>= 1) ce += __shfl_down(ce, off);
    __shared__ float sC[4];
    if ((t & 63) == 0) sC[t >> 6] = ce;
    __syncthreads();
    if (t == 0) pce[blockIdx.x] = sC[0] + sC[1] + sC[2] + sC[3];
}

// ---------------- finalize: sum partials ----------------
__global__ __launch_bounds__(256)
void finalize_kernel(const float* __restrict__ pll, const float* __restrict__ pce,
                     float* __restrict__ out) {
    const int t = threadIdx.x;
    float a = 0.0f, b = 0.0f;
    for (int i = t; i < NB_NODE * 4; i += 256) a += pll[i];
    for (int i = t; i < NB_CE; i += 256) b += pce[i];
    for (int off = 32; off; off >>= 1) {
        a += __shfl_down(a, off);
        b += __shfl_down(b, off);
    }
    __shared__ float sA[4], sB[4];
    if ((t & 63) == 0) { sA[t >> 6] = a; sB[t >> 6] = b; }
    __syncthreads();
    if (t == 0) {
        float ll = sA[0] + sA[1] + sA[2] + sA[3];
        float ce = sB[0] + sB[1] + sB[2] + sB[3];
        out[0] = ll / (float)N_NODES;
        out[1] = -ce / (float)N_NODES;
    }
}

extern "C" void kernel_launch(void* const* d_in, const int* in_sizes, int n_in,
                              void* d_out, int out_size, void* d_ws, size_t ws_size,
                              hipStream_t stream) {
    const float* X   = (const float*)d_in[0];
    const float* Mu  = (const float*)d_in[1];
    const float* Var = (const float*)d_in[2];
    const float* W   = (const float*)d_in[3];
    const float* S   = (const float*)d_in[4];
    const float* Wl  = (const float*)d_in[5];
    const float* bl  = (const float*)d_in[6];
    const float* Wr  = (const float*)d_in[7];
    const float* br  = (const float*)d_in[8];
    const float* att = (const float*)d_in[9];
    const int*   ei  = (const int*)d_in[10];
    float* out = (float*)d_out;
    float* ws  = (float*)d_ws;

    unsigned short* Tb     = (unsigned short*)(ws + OFF_T);
    float*          q3     = ws + OFF_Q3;
    float*          srcRec = ws + OFF_SRC;
    float*          dstRec = ws + OFF_DST;
    float*          contrib= ws + OFF_CON;
    float*          den    = ws + OFF_DEN;
    float*          pll    = ws + OFF_PLL;
    float*          pce    = ws + OFF_PCE;

    prep_kernel<<<(N_NODES + 255) / 256, 256, 0, stream>>>(Var, Mu, Wl, Wr, Tb, den, q3);
    node_kernel<<<NB_NODE, 256, 0, stream>>>(X, W, S, bl, br, Tb, q3,
                                             out + 2, srcRec, dstRec, pll);
    edge1_kernel<<<NB_E1, 256, 0, stream>>>(ei, srcRec, dstRec, att, contrib, den);
    edge2_kernel<<<NB_CE, 256, 0, stream>>>(ei, contrib, den, pce);
    finalize_kernel<<<1, 256, 0, stream>>>(pll, pce, out);
}